// Round 1
// baseline (44.028 us; speedup 1.0000x reference)
//
#include <hip/hip_runtime.h>
#include <hip/hip_bf16.h>
#include <math.h>

// Problem constants (fixed by setup_inputs)
#define BB 4
#define NN 48
#define SS 32
#define AA 16
#define AI 8
#define EE 512
#define KK 16

// ws layout (byte offsets)
#define WS_FLAG   0        // 1 int
#define WS_CU     256      // 512 floats  (S*A)
#define WS_CBIN   2304     // 8192 floats (S*S*AI)
#define WS_BEAM   35072    // B*N*K ints = 3072
#define WS_NGOLD  47360    // B*N floats = 192
#define WS_EGOLD  48128    // B*E floats = 2048
// total ~56 KB

__device__ __forceinline__ bool read_mask(const void* p, int idx, int flag) {
    if (flag == 1) return ((const unsigned char*)p)[idx] != 0;
    if (flag == 2) return ((const float*)p)[idx] != 0.0f;
    return ((const int*)p)[idx] != 0;
}

// ---------------- Kernel 1: detect bool storage + precompute coefficients ----
__global__ void prep_kernel(const void* bmask, const void* imask,
                            const float* wpu, const float* wpb,
                            int* flag_p, float* cu, float* cbin) {
    __shared__ int s_flag;
    int tid = threadIdx.x;
    if (tid == 0) {
        // behavior_masks has 512 elements (bernoulli 0.5). Reading the first
        // 512 BYTES as 128 uint words is safe in all 3 candidate layouts.
        const unsigned int* w = (const unsigned int*)bmask;
        bool anyF = false, anyGt1 = false;
        for (int i = 0; i < 128; ++i) {
            unsigned int v = w[i];
            if (v == 0x3F800000u) anyF = true;
            else if (v > 1u) anyGt1 = true;
        }
        int f = anyF ? 2 : (anyGt1 ? 1 : 0);
        s_flag = f;
        *flag_p = f;
    }
    __syncthreads();
    int flag = s_flag;

    // cu[s*A+a] = bmask[s,a] ? wpu[s]/acnt[s] : 0
    if (tid < SS) {
        int s = tid;
        float cnt = 0.f;
        for (int a = 0; a < AA; ++a)
            cnt += read_mask(bmask, s * AA + a, flag) ? 1.f : 0.f;
        if (cnt == 0.f) cnt = 1.f;
        float w = wpu[s] / cnt;
        for (int a = 0; a < AA; ++a)
            cu[s * AA + a] = read_mask(bmask, s * AA + a, flag) ? w : 0.f;
    }

    // cbin[(s1*S+s2)*AI+a] = imask[s1,s2,a] ? wpb[s1,s2]/icnt[s1,s2] : 0
    for (int p = tid; p < SS * SS; p += blockDim.x) {
        float cnt = 0.f;
        for (int a = 0; a < AI; ++a)
            cnt += read_mask(imask, p * AI + a, flag) ? 1.f : 0.f;
        if (cnt == 0.f) cnt = 1.f;
        float w = wpb[p] / cnt;
        for (int a = 0; a < AI; ++a)
            cbin[p * AI + a] = read_mask(imask, p * AI + a, flag) ? w : 0.f;
    }
}

// ---------------- Kernel 2: per-node weighted unary, beam top-16, unary gold -
__global__ void node_kernel(const float* __restrict__ unaries,
                            const float* __restrict__ behaviors,
                            const void* masks, const int* __restrict__ targets,
                            const int* __restrict__ flag_p,
                            const float* __restrict__ cu,
                            int* __restrict__ beam,
                            float* __restrict__ node_gold) {
    int node = blockIdx.x;          // node = b*N + n
    int b = node / NN;
    int lane = threadIdx.x;         // 0..63, only 0..31 own a state
    int flag = *flag_p;

    float m = read_mask(masks, node, flag) ? 1.f : 0.f;
    int tgt = targets[node];

    float val, key;
    if (lane < SS) {
        int s = lane;
        float u = unaries[node * SS + s];
        const float4* bp = (const float4*)(behaviors + ((size_t)node * SS + s) * AA);
        const float4* cp = (const float4*)(cu + s * AA);
        float bu = 0.f;
        #pragma unroll
        for (int r = 0; r < 4; ++r) {
            float4 x = bp[r], c = cp[r];
            bu += x.x * c.x + x.y * c.y + x.z * c.z + x.w * c.w;
        }
        val = m * (u + bu);                         // weighted_unaries
        key = (s == tgt) ? INFINITY : val;          // _u with target -> +inf
    } else {
        val = -INFINITY;
        key = -INFINITY;
    }

    // rank = #states with strictly greater key, ties broken by lower index
    int rank = 0;
    #pragma unroll
    for (int t = 0; t < SS; ++t) {
        float kt = __shfl(key, t, 64);
        rank += (kt > key) || (kt == key && t < lane);
    }
    bool sel = (lane < SS) && (rank < KK);
    if (sel) beam[node * KK + rank] = lane;

    // log-softmax over the selected 16 ORIGINAL values; gold = val[target]
    float mv = sel ? val : -INFINITY;
    #pragma unroll
    for (int off = 32; off >= 1; off >>= 1)
        mv = fmaxf(mv, __shfl_xor(mv, off, 64));
    float se = sel ? expf(val - mv) : 0.f;
    #pragma unroll
    for (int off = 32; off >= 1; off >>= 1)
        se += __shfl_xor(se, off, 64);
    float vt = __shfl(val, tgt, 64);                // weighted at target
    if (lane == 0)
        node_gold[node] = (m > 0.f) ? (vt - mv - logf(se)) : 0.f;
}

// ---------------- Kernel 3: per-edge K*K beam-pair gather + logsumexp --------
__global__ void edge_kernel(const float* __restrict__ interactions,
                            const int* __restrict__ edges,
                            const void* binmask,
                            const int* __restrict__ flag_p,
                            const float* __restrict__ cbin,
                            const int* __restrict__ beam,
                            float* __restrict__ edge_gold) {
    int be = blockIdx.x;            // be = b*E + e
    int b = be / EE;
    int tid = threadIdx.x;          // 256 = K*K
    int flag = *flag_p;

    int n1 = edges[be * 2 + 0];
    int n2 = edges[be * 2 + 1];

    int i = tid >> 4, j = tid & 15;
    int s1 = beam[(b * NN + n1) * KK + i];
    int s2 = beam[(b * NN + n2) * KK + j];

    size_t base = ((size_t)((b * NN + n1) * NN + n2) * (SS * SS)
                   + (size_t)(s1 * SS + s2)) * AI;
    float4 x0 = *(const float4*)(interactions + base);
    float4 x1 = *(const float4*)(interactions + base + 4);
    int ci = (s1 * SS + s2) * AI;
    float4 c0 = *(const float4*)(cbin + ci);
    float4 c1 = *(const float4*)(cbin + ci + 4);
    float phi = x0.x * c0.x + x0.y * c0.y + x0.z * c0.z + x0.w * c0.w
              + x1.x * c1.x + x1.y * c1.y + x1.z * c1.z + x1.w * c1.w;

    __shared__ float sred[4];
    float v = phi;
    #pragma unroll
    for (int off = 32; off >= 1; off >>= 1)
        v = fmaxf(v, __shfl_xor(v, off, 64));
    if ((tid & 63) == 0) sred[tid >> 6] = v;
    __syncthreads();
    float mx = fmaxf(fmaxf(sred[0], sred[1]), fmaxf(sred[2], sred[3]));
    __syncthreads();
    float e = expf(phi - mx);
    #pragma unroll
    for (int off = 32; off >= 1; off >>= 1)
        e += __shfl_xor(e, off, 64);
    if ((tid & 63) == 0) sred[tid >> 6] = e;
    __syncthreads();
    if (tid == 0) {
        float s = sred[0] + sred[1] + sred[2] + sred[3];
        float gold = phi - mx - logf(s);            // phi here is phi[0][0]
        bool bm = read_mask(binmask, be, flag);
        edge_gold[be] = bm ? gold : 0.f;
    }
}

// ---------------- Kernel 4: final reduction -> nll ---------------------------
__global__ void final_kernel(const void* masks, const int* __restrict__ flag_p,
                             const float* __restrict__ node_gold,
                             const float* __restrict__ edge_gold,
                             float* __restrict__ out) {
    int tid = threadIdx.x;          // 256 threads = 4 waves, wave w = batch b
    int b = tid >> 6;
    int lane = tid & 63;
    int flag = *flag_p;

    float sum = 0.f, cnt = 0.f;
    for (int n = lane; n < NN; n += 64) {
        sum += node_gold[b * NN + n];
        cnt += read_mask(masks, b * NN + n, flag) ? 1.f : 0.f;
    }
    for (int e = lane; e < EE; e += 64)
        sum += edge_gold[b * EE + e];

    #pragma unroll
    for (int off = 32; off >= 1; off >>= 1) {
        sum += __shfl_xor(sum, off, 64);
        cnt += __shfl_xor(cnt, off, 64);
    }
    __shared__ float sp[4];
    if (lane == 0) sp[b] = sum / cnt;
    __syncthreads();
    if (tid == 0)
        out[0] = -(sp[0] + sp[1] + sp[2] + sp[3]) * (1.f / BB);
}

extern "C" void kernel_launch(void* const* d_in, const int* in_sizes, int n_in,
                              void* d_out, int out_size, void* d_ws, size_t ws_size,
                              hipStream_t stream) {
    const float* unaries      = (const float*)d_in[0];
    const float* behaviors    = (const float*)d_in[1];
    const float* interactions = (const float*)d_in[2];
    const float* wpu          = (const float*)d_in[3];
    const float* wpb          = (const float*)d_in[4];
    const void*  masks        = d_in[5];
    const void*  bmask        = d_in[6];
    const void*  imask        = d_in[7];
    const int*   edges        = (const int*)d_in[8];
    const void*  binmask      = d_in[9];
    const int*   targets      = (const int*)d_in[10];
    float* out = (float*)d_out;

    char* ws = (char*)d_ws;
    int*   flag_p    = (int*)(ws + WS_FLAG);
    float* cu        = (float*)(ws + WS_CU);
    float* cbin      = (float*)(ws + WS_CBIN);
    int*   beam      = (int*)(ws + WS_BEAM);
    float* node_gold = (float*)(ws + WS_NGOLD);
    float* edge_gold = (float*)(ws + WS_EGOLD);

    prep_kernel<<<1, 256, 0, stream>>>(bmask, imask, wpu, wpb, flag_p, cu, cbin);
    node_kernel<<<BB * NN, 64, 0, stream>>>(unaries, behaviors, masks, targets,
                                            flag_p, cu, beam, node_gold);
    edge_kernel<<<BB * EE, 256, 0, stream>>>(interactions, edges, binmask,
                                             flag_p, cbin, beam, edge_gold);
    final_kernel<<<1, 256, 0, stream>>>(masks, flag_p, node_gold, edge_gold, out);
}